// Round 14
// baseline (2228.253 us; speedup 1.0000x reference)
//
#include <hip/hip_runtime.h>
#include <hip/hip_bf16.h>

// ---------------------------------------------------------------------------
// Swin window attention, MI355X gfx950 — MEGA-FUSED v2.
// prep (bf16 weights + pad-premasked frag bias) ->
// mega (per-window: x gather -> LDS; QKV GEMM (W from L2) with q/k -> GLOBAL
//       (L2-hot round-trip), v^T -> global vt; attention (swapped QK^T,
//       lane-local softmax); proj -> rolled fp32 scatter).
// v2: q/k go through L2 instead of LDS -> LDS = 63,040 B -> TWO blocks/CU
// (24 waves) so independent blocks' phases overlap (R13 was 1 block, 90% stall).
// Workspace: 256.4 MB.
// ---------------------------------------------------------------------------

typedef __bf16 bf16x8 __attribute__((ext_vector_type(8)));
typedef float  floatx4 __attribute__((ext_vector_type(4)));
typedef short  short8  __attribute__((ext_vector_type(8)));

#define MFMA16(a, b, c) __builtin_amdgcn_mfma_f32_16x16x32_bf16((a), (b), (c), 0, 0, 0)

static __device__ __forceinline__ int src_off(int gm) {
  int win = gm / 49, t = gm - win * 49;
  int b = win >> 6, rr = win & 63;
  int wi = rr >> 3, wj = rr & 7;
  int ty = t / 7, tx = t - ty * 7;
  int y = wi * 7 + ty + 4; if (y >= 56) y -= 56;
  int x = wj * 7 + tx + 4; if (x >= 56) x -= 56;
  return ((b * 56 + y) * 56 + x) * 384;
}

static __device__ __forceinline__ int dst_off(int gm) {
  int win = gm / 49, t = gm - win * 49;
  int b = win >> 6, rr = win & 63;
  int wi = rr >> 3, wj = rr & 7;
  int ty = t / 7, tx = t - ty * 7;
  int y = wi * 7 + ty + 3; if (y >= 56) y -= 56;
  int x = wj * 7 + tx + 3; if (x >= 56) x -= 56;
  return ((b * 56 + y) * 56 + x) * 384;
}

static __device__ __forceinline__ float bf_lo(unsigned u) {
  union { unsigned v; float f; } c; c.v = u << 16; return c.f;
}
static __device__ __forceinline__ float bf_hi(unsigned u) {
  union { unsigned v; float f; } c; c.v = u & 0xFFFF0000u; return c.f;
}

// ---------------------------------------------------------------------------
// prep: bf16 weight copies + bias2 in the TRANSPOSED (S^T) fragment layout,
// PRE-MASKED with the pad mask (m>=49 || n>=49 -> -1e30).
// bias2[head][mi][ni][lane(64)][r(4)], m = mi*16+(lane&15),
// n = ni*16+(lane>>4)*4+r.
__global__ __launch_bounds__(256) void prep_kernel(
    const float* __restrict__ w_qkv, const float* __restrict__ w_proj,
    const float* __restrict__ rel_table,
    __hip_bfloat16* __restrict__ wqkv_bf, __hip_bfloat16* __restrict__ wproj_bf,
    __hip_bfloat16* __restrict__ bias2) {
  const int N1 = 3 * 384 * 384;   // 442368
  const int N2 = 384 * 384;       // 147456
  const int N3 = 12 * 4 * 4 * 64 * 4;  // 196608
  int i = blockIdx.x * 256 + threadIdx.x;  // grid 3072*256 = N1+N2+N3
  if (i < N1) wqkv_bf[i] = __float2bfloat16(w_qkv[i]);
  int j = i - N1;
  if (j >= 0 && j < N2) wproj_bf[j] = __float2bfloat16(w_proj[j]);
  int k = i - N1 - N2;
  if (k >= 0 && k < N3) {
    int r = k & 3;
    int lp = (k >> 2) & 63;
    int ni = (k >> 8) & 3;
    int mi = (k >> 10) & 3;
    int head = k >> 12;
    int m = mi * 16 + (lp & 15);
    int n = ni * 16 + (lp >> 4) * 4 + r;
    float val = -1e30f;
    if (m < 49 && n < 49) {
      int dy = m / 7 - n / 7 + 6;
      int dx = m % 7 - n % 7 + 6;
      val = rel_table[(dy * 13 + dx) * 12 + head];
    }
    bias2[k] = __float2bfloat16(val);
  }
}

// ---------------------------------------------------------------------------
// Mega kernel v2: 1 block = 1 window, 768 threads = 12 waves.
// LDS: xo(49x392, x then O) + p(12x16x64 swizzled) = 63,040 B -> 2 blocks/CU.
// q/k round-trip through global (L2-hot: written one barrier before the read).
__global__ __launch_bounds__(768, 6) void mega_kernel(
    const float* __restrict__ x, const __hip_bfloat16* __restrict__ wq,
    const float* __restrict__ bqkv, const __hip_bfloat16* __restrict__ bias2,
    const __hip_bfloat16* __restrict__ wp, const float* __restrict__ bproj,
    __hip_bfloat16* __restrict__ qb, __hip_bfloat16* __restrict__ kb,
    __hip_bfloat16* __restrict__ vt, float* __restrict__ out) {
  __shared__ __hip_bfloat16 xo_lds[49][392];    // 38,416 B (x, later O)
  __shared__ __hip_bfloat16 p_lds[12][16][64];  // 24,576 B (chunk-swizzled)

  int blk = blockIdx.x;                         // 2048 = 8 * 256
  int win = (blk & 7) * 256 + (blk >> 3);       // XCD-chunked swizzle
  int tid = threadIdx.x;
  int wv = tid >> 6, l = tid & 63;              // wave 0..11
  int g = l >> 4, q16 = l & 15;
  const int sw = q16 & 7;                       // p_lds chunk swizzle key

  floatx4 zc;
  zc[0] = zc[1] = zc[2] = zc[3] = 0.f;

  // ---- phase 0: x gather (roll -4 + window) + fp32->bf16 into xo_lds ----
  for (int i = tid; i < 49 * 48; i += 768) {
    int row = i / 48, c8 = (i - row * 48) * 8;
    int so = src_off(win * 49 + row) + c8;
    floatx4 a = *(const floatx4*)(x + so);
    floatx4 b = *(const floatx4*)(x + so + 4);
    union { __hip_bfloat16 h[8]; short8 s; } u;
#pragma unroll
    for (int e = 0; e < 4; ++e) {
      u.h[e]     = __float2bfloat16(a[e]);
      u.h[4 + e] = __float2bfloat16(b[e]);
    }
    *(short8*)&xo_lds[row][c8] = u.s;
  }
  __syncthreads();

  // ---- phase 1: per-window QKV GEMM. wave w -> cols [w*96, w*96+96).
  // waves 0-3: q (scaled) -> qb; 4-7: k -> kb; 8-11: v (C^T) -> vt.
  {
    const bool isv = (wv >= 8);
    const bool isq = (wv < 4);
    __hip_bfloat16* gdst = isq ? qb : kb;
#pragma unroll 1
    for (int pass = 0; pass < 2; ++pass) {
      int n0 = wv * 96 + pass * 48;
      floatx4 acc[12];
#pragma unroll
      for (int i = 0; i < 12; ++i) acc[i] = zc;

#pragma unroll
      for (int ks = 0; ks < 12; ++ks) {
        int k0 = ks * 32;
        bf16x8 af[4], bf[3];
#pragma unroll
        for (int mi = 0; mi < 4; ++mi) {
          int row = mi * 16 + q16;
          row = row < 49 ? row : 48;            // pad rows -> dup (discarded)
          af[mi] = *(const bf16x8*)&xo_lds[row][k0 + g * 8];
        }
#pragma unroll
        for (int ni = 0; ni < 3; ++ni)
          bf[ni] = *(const bf16x8*)(wq + (size_t)(n0 + ni * 16 + q16) * 384 + k0 + g * 8);
        __builtin_amdgcn_s_setprio(1);
        if (!isv) {
#pragma unroll
          for (int mi = 0; mi < 4; ++mi)
#pragma unroll
            for (int ni = 0; ni < 3; ++ni)
              acc[mi * 3 + ni] = MFMA16(af[mi], bf[ni], acc[mi * 3 + ni]);
        } else {
          // swapped: C^T[d][t]; A = W rows (d), B = x rows (t)
#pragma unroll
          for (int ai = 0; ai < 3; ++ai)
#pragma unroll
            for (int bj = 0; bj < 4; ++bj)
              acc[ai * 4 + bj] = MFMA16(bf[ai], af[bj], acc[ai * 4 + bj]);
        }
        __builtin_amdgcn_s_setprio(0);
      }

      if (!isv) {
        // q/k: C[m][n], lanes q16 -> consecutive n (32B runs). Guard m<49.
#pragma unroll
        for (int ni = 0; ni < 3; ++ni) {
          int n = n0 + ni * 16 + q16;
          float bn = bqkv[n];
          int nn = isq ? n : (n - 384);
#pragma unroll
          for (int mi = 0; mi < 4; ++mi) {
#pragma unroll
            for (int r = 0; r < 4; ++r) {
              int m = mi * 16 + g * 4 + r;
              if (m < 49) {
                float v = acc[mi * 3 + ni][r] + bn;
                if (isq) v *= 0.17677669529663687f;   // 1/sqrt(32)
                gdst[(size_t)(win * 49 + m) * 384 + nn] = __float2bfloat16(v);
              }
            }
          }
        }
      } else {
        // v: C^T[d][t], lanes q16 -> consecutive t (32B runs into vt rows);
        // pad cols t=49..63 get finite garbage, multiplied by P == 0 later.
#pragma unroll
        for (int ai = 0; ai < 3; ++ai) {
#pragma unroll
          for (int r = 0; r < 4; ++r) {
            int n = n0 + ai * 16 + g * 4 + r;     // 768..1151
            float bn = bqkv[n];
            int d = n - 768;
#pragma unroll
            for (int bj = 0; bj < 4; ++bj) {
              int t = bj * 16 + q16;
              vt[((size_t)win * 384 + d) * 64 + t] =
                  __float2bfloat16(acc[ai * 4 + bj][r] + bn);
            }
          }
        }
      }
    }
  }
  __syncthreads();   // drains vmcnt(0): qb/kb/vt visible via L2 (same XCD)

  // ---- phase 2: attention, one head per wave (swapped QK^T) ----
  {
    const int head = wv;
    int wr = win & 63;
    const bool lastrow = ((wr >> 3) == 7);
    const bool lastcol = ((wr & 7) == 7);

    // shift-mask badbits only for boundary windows (uniform branch);
    // pad mask is pre-baked into bias2 = -1e30.
    unsigned long long badbits = 0ull;
    if (lastrow || lastcol) {
#pragma unroll
      for (int mi = 0; mi < 4; ++mi) {
        int m = mi * 16 + q16;
        int m7 = m % 7;
        bool m28 = (m >= 28), m74 = (m7 >= 4);
#pragma unroll
        for (int ni = 0; ni < 4; ++ni) {
#pragma unroll
          for (int r = 0; r < 4; ++r) {
            int n = ni * 16 + g * 4 + r;
            bool bad = (lastrow && (m28 != (n >= 28))) ||
                       (lastcol && (m74 != ((n % 7) >= 4)));
            if (bad) badbits |= (1ull << (mi * 16 + ni * 4 + r));
          }
        }
      }
    }

    const __hip_bfloat16* qp = qb + (size_t)(win * 49) * 384 + head * 32 + g * 8;
    const __hip_bfloat16* kp = kb + (size_t)(win * 49) * 384 + head * 32 + g * 8;

    bf16x8 aq[4], bk[4];
#pragma unroll
    for (int mi = 0; mi < 4; ++mi) {
      int row = mi * 16 + q16;
      row = row < 49 ? row : 48;                // pad rows masked via bias
      aq[mi] = *(const bf16x8*)(qp + row * 384);
      bk[mi] = *(const bf16x8*)(kp + row * 384);
    }

    floatx4 st[4][4];                           // [ni][mi] = S^T
    __builtin_amdgcn_s_setprio(1);
#pragma unroll
    for (int ni = 0; ni < 4; ++ni)
#pragma unroll
      for (int mi = 0; mi < 4; ++mi)
        st[ni][mi] = MFMA16(bk[ni], aq[mi], zc);
    __builtin_amdgcn_s_setprio(0);

    // V B-frags (written by this block in phase 1; L2-resident)
    const __hip_bfloat16* vp = vt + ((size_t)win * 384 + head * 32) * 64;
    bf16x8 bv[2][2];
#pragma unroll
    for (int ks = 0; ks < 2; ++ks)
#pragma unroll
      for (int n2 = 0; n2 < 2; ++n2)
        bv[ks][n2] = *(const bf16x8*)(vp + (n2 * 16 + q16) * 64 + ks * 32 + g * 8);

    const __hip_bfloat16* b2 = bias2 + (size_t)head * 4096;
    __hip_bfloat16* pw = &p_lds[wv][0][0];

#pragma unroll
    for (int mi = 0; mi < 4; ++mi) {
      uint2 braw[4];
#pragma unroll
      for (int ni = 0; ni < 4; ++ni)
        braw[ni] = *(const uint2*)(b2 + ((mi * 4 + ni) * 64 + l) * 4);

      float vals[4][4];
      float mx = -1e30f;
#pragma unroll
      for (int ni = 0; ni < 4; ++ni) {
#pragma unroll
        for (int r = 0; r < 4; ++r) {
          float bb = (r == 0) ? bf_lo(braw[ni].x) : (r == 1) ? bf_hi(braw[ni].x)
                     : (r == 2) ? bf_lo(braw[ni].y) : bf_hi(braw[ni].y);
          float v = st[ni][mi][r] + bb;         // pad entries: bb = -1e30
          if ((badbits >> (mi * 16 + ni * 4 + r)) & 1) v = -1e30f;
          vals[ni][r] = v;
          mx = fmaxf(mx, v);
        }
      }
      mx = fmaxf(mx, __shfl_xor(mx, 16));
      mx = fmaxf(mx, __shfl_xor(mx, 32));
      float sum = 0.f;
#pragma unroll
      for (int ni = 0; ni < 4; ++ni) {
#pragma unroll
        for (int r = 0; r < 4; ++r) {
          float p = __expf(vals[ni][r] - mx);   // masked -> exact 0
          vals[ni][r] = p;
          sum += p;
        }
      }
      sum += __shfl_xor(sum, 16);
      sum += __shfl_xor(sum, 32);
      float inv = 1.0f / sum;

      // normalized P -> swizzled 8B writes (R12 layout)
#pragma unroll
      for (int ni = 0; ni < 4; ++ni) {
        union { __hip_bfloat16 h[4]; unsigned long long u; } pk;
#pragma unroll
        for (int r = 0; r < 4; ++r) pk.h[r] = __float2bfloat16(vals[ni][r] * inv);
        int pc = (2 * ni + (g >> 1)) ^ sw;
        *(unsigned long long*)(pw + q16 * 64 + pc * 8 + (g & 1) * 4) = pk.u;
      }

      bf16x8 av0 = *(const bf16x8*)(pw + q16 * 64 + (g ^ sw) * 8);
      bf16x8 av1 = *(const bf16x8*)(pw + q16 * 64 + ((4 + g) ^ sw) * 8);
      floatx4 o2[2];
      o2[0] = o2[1] = zc;
#pragma unroll
      for (int n2 = 0; n2 < 2; ++n2) {
        o2[n2] = MFMA16(av0, bv[0][n2], o2[n2]);
        o2[n2] = MFMA16(av1, bv[1][n2], o2[n2]);
      }
#pragma unroll
      for (int r = 0; r < 4; ++r) {
        int m = mi * 16 + g * 4 + r;
        if (m < 49) {
#pragma unroll
          for (int n2 = 0; n2 < 2; ++n2)
            xo_lds[m][head * 32 + n2 * 16 + q16] = __float2bfloat16(o2[n2][r]);
        }
      }
    }
  }
  __syncthreads();                              // all heads' O in xo_lds

  // ---- phase 3: proj. wave wv -> output cols [wv*32, wv*32+32) ----
  {
    floatx4 pacc[4][2];
#pragma unroll
    for (int i = 0; i < 4; ++i)
#pragma unroll
      for (int j = 0; j < 2; ++j) pacc[i][j] = zc;

    for (int k0 = 0; k0 < 384; k0 += 32) {
      bf16x8 af[4], bfr[2];
#pragma unroll
      for (int mi = 0; mi < 4; ++mi) {
        int row = mi * 16 + q16;
        row = row < 49 ? row : 48;
        af[mi] = *(const bf16x8*)&xo_lds[row][k0 + g * 8];
      }
#pragma unroll
      for (int ni = 0; ni < 2; ++ni) {
        int brow = wv * 32 + ni * 16 + q16;
        bfr[ni] = *(const bf16x8*)(wp + (size_t)brow * 384 + k0 + g * 8);
      }
      __builtin_amdgcn_s_setprio(1);
#pragma unroll
      for (int mi = 0; mi < 4; ++mi)
#pragma unroll
        for (int ni = 0; ni < 2; ++ni)
          pacc[mi][ni] = MFMA16(af[mi], bfr[ni], pacc[mi][ni]);
      __builtin_amdgcn_s_setprio(0);
    }

#pragma unroll
    for (int mi = 0; mi < 4; ++mi) {
#pragma unroll
      for (int r = 0; r < 4; ++r) {
        int m = mi * 16 + g * 4 + r;
        if (m < 49) {
          int off = dst_off(win * 49 + m);
#pragma unroll
          for (int ni = 0; ni < 2; ++ni) {
            int n = wv * 32 + ni * 16 + q16;
            out[off + n] = pacc[mi][ni][r] + bproj[n];
          }
        }
      }
    }
  }
}

// ---------------------------------------------------------------------------
extern "C" void kernel_launch(void* const* d_in, const int* in_sizes, int n_in,
                              void* d_out, int out_size, void* d_ws, size_t ws_size,
                              hipStream_t stream) {
  const float* x         = (const float*)d_in[0];
  const float* w_qkv     = (const float*)d_in[1];
  const float* b_qkv     = (const float*)d_in[2];
  const float* w_proj    = (const float*)d_in[3];
  const float* b_proj    = (const float*)d_in[4];
  const float* rel_table = (const float*)d_in[5];
  float* out = (float*)d_out;

  char* ws = (char*)d_ws;
  // Workspace layout (total 256,376,832 B):
  const size_t OFF_WQKV  = 0;                        //   884,736
  const size_t OFF_WPROJ = 884736;                   //   294,912
  const size_t OFF_BIAS2 = 1179648;                  //   393,216
  const size_t OFF_Q     = 1572864;                  //  77,070,336
  const size_t OFF_K     = OFF_Q + 77070336;         //  77,070,336
  const size_t OFF_VT    = OFF_K + 77070336;         // 100,663,296 (v^T, 64-pad)

  __hip_bfloat16* wqkv_bf  = (__hip_bfloat16*)(ws + OFF_WQKV);
  __hip_bfloat16* wproj_bf = (__hip_bfloat16*)(ws + OFF_WPROJ);
  __hip_bfloat16* bias2    = (__hip_bfloat16*)(ws + OFF_BIAS2);
  __hip_bfloat16* qb       = (__hip_bfloat16*)(ws + OFF_Q);
  __hip_bfloat16* kb       = (__hip_bfloat16*)(ws + OFF_K);
  __hip_bfloat16* vt       = (__hip_bfloat16*)(ws + OFF_VT);

  // qb/kb/vt are fully (re)written by each mega launch before being read;
  // vt pad cols only ever multiply exactly-zero P entries.

  prep_kernel<<<3072, 256, 0, stream>>>(w_qkv, w_proj, rel_table, wqkv_bf, wproj_bf, bias2);
  mega_kernel<<<2048, 768, 0, stream>>>(x, wqkv_bf, b_qkv, bias2, wproj_bf, b_proj,
                                        qb, kb, vt, out);
}

// Round 15
// 618.019 us; speedup vs baseline: 3.6055x; 3.6055x over previous
//
#include <hip/hip_runtime.h>
#include <hip/hip_bf16.h>

// ---------------------------------------------------------------------------
// Swin window attention, MI355X gfx950 — MEGA-FUSED v3 (code-size-lean).
// prep (bf16 weights + pad-premasked frag bias) ->
// mega (per-window: x gather -> LDS; QKV GEMM (W from L2, q/k -> LDS,
//       v^T -> global vt); attention (swapped QK^T, lane-local softmax,
//       PER-MI rolled loop); proj -> rolled fp32 scatter).
// v3 = R13 with the three hot loops ROLLED (#pragma unroll 1) to shrink the
// kernel from ~40 KB (L1I=32 KB thrash suspect) to ~7 KB of hot code, with
// manual clamped prefetch of the global B-fragments inside rolled loops.
// Workspace: 102.2 MB. LDS: 139.8 KB -> 1 block (12 waves)/CU.
// ---------------------------------------------------------------------------

typedef __bf16 bf16x8 __attribute__((ext_vector_type(8)));
typedef float  floatx4 __attribute__((ext_vector_type(4)));
typedef short  short8  __attribute__((ext_vector_type(8)));

#define MFMA16(a, b, c) __builtin_amdgcn_mfma_f32_16x16x32_bf16((a), (b), (c), 0, 0, 0)

static __device__ __forceinline__ int src_off(int gm) {
  int win = gm / 49, t = gm - win * 49;
  int b = win >> 6, rr = win & 63;
  int wi = rr >> 3, wj = rr & 7;
  int ty = t / 7, tx = t - ty * 7;
  int y = wi * 7 + ty + 4; if (y >= 56) y -= 56;
  int x = wj * 7 + tx + 4; if (x >= 56) x -= 56;
  return ((b * 56 + y) * 56 + x) * 384;
}

static __device__ __forceinline__ int dst_off(int gm) {
  int win = gm / 49, t = gm - win * 49;
  int b = win >> 6, rr = win & 63;
  int wi = rr >> 3, wj = rr & 7;
  int ty = t / 7, tx = t - ty * 7;
  int y = wi * 7 + ty + 3; if (y >= 56) y -= 56;
  int x = wj * 7 + tx + 3; if (x >= 56) x -= 56;
  return ((b * 56 + y) * 56 + x) * 384;
}

static __device__ __forceinline__ float bf_lo(unsigned u) {
  union { unsigned v; float f; } c; c.v = u << 16; return c.f;
}
static __device__ __forceinline__ float bf_hi(unsigned u) {
  union { unsigned v; float f; } c; c.v = u & 0xFFFF0000u; return c.f;
}

// ---------------------------------------------------------------------------
// prep: bf16 weight copies + bias2 in the TRANSPOSED (S^T) fragment layout,
// PRE-MASKED with the pad mask (m>=49 || n>=49 -> -1e30).
// bias2[head][mi][ni][lane(64)][r(4)], m = mi*16+(lane&15),
// n = ni*16+(lane>>4)*4+r.
__global__ __launch_bounds__(256) void prep_kernel(
    const float* __restrict__ w_qkv, const float* __restrict__ w_proj,
    const float* __restrict__ rel_table,
    __hip_bfloat16* __restrict__ wqkv_bf, __hip_bfloat16* __restrict__ wproj_bf,
    __hip_bfloat16* __restrict__ bias2) {
  const int N1 = 3 * 384 * 384;   // 442368
  const int N2 = 384 * 384;       // 147456
  const int N3 = 12 * 4 * 4 * 64 * 4;  // 196608
  int i = blockIdx.x * 256 + threadIdx.x;  // grid 3072*256 = N1+N2+N3
  if (i < N1) wqkv_bf[i] = __float2bfloat16(w_qkv[i]);
  int j = i - N1;
  if (j >= 0 && j < N2) wproj_bf[j] = __float2bfloat16(w_proj[j]);
  int k = i - N1 - N2;
  if (k >= 0 && k < N3) {
    int r = k & 3;
    int lp = (k >> 2) & 63;
    int ni = (k >> 8) & 3;
    int mi = (k >> 10) & 3;
    int head = k >> 12;
    int m = mi * 16 + (lp & 15);
    int n = ni * 16 + (lp >> 4) * 4 + r;
    float val = -1e30f;
    if (m < 49 && n < 49) {
      int dy = m / 7 - n / 7 + 6;
      int dx = m % 7 - n % 7 + 6;
      val = rel_table[(dy * 13 + dx) * 12 + head];
    }
    bias2[k] = __float2bfloat16(val);
  }
}

// ---------------------------------------------------------------------------
// Mega kernel v3: 1 block = 1 window, 768 threads = 12 waves.
// LDS: xo(49x392, x then O) + q(49x392) + k(49x392) + p(12x16x64 swizzled)
//    = 139,824 B -> 1 block/CU, 3 waves/SIMD.
__global__ __launch_bounds__(768, 3) void mega_kernel(
    const float* __restrict__ x, const __hip_bfloat16* __restrict__ wq,
    const float* __restrict__ bqkv, const __hip_bfloat16* __restrict__ bias2,
    const __hip_bfloat16* __restrict__ wp, const float* __restrict__ bproj,
    __hip_bfloat16* __restrict__ vt, float* __restrict__ out) {
  __shared__ __hip_bfloat16 xo_lds[49][392];    // 38,416 B (x, later O)
  __shared__ __hip_bfloat16 q_lds[49][392];     // 38,416 B (q, pre-scaled)
  __shared__ __hip_bfloat16 k_lds[49][392];     // 38,416 B
  __shared__ __hip_bfloat16 p_lds[12][16][64];  // 24,576 B (chunk-swizzled)

  int blk = blockIdx.x;                         // 2048 = 8 * 256
  int win = (blk & 7) * 256 + (blk >> 3);       // XCD-chunked swizzle
  int tid = threadIdx.x;
  int wv = tid >> 6, l = tid & 63;              // wave 0..11
  int g = l >> 4, q16 = l & 15;
  const int sw = q16 & 7;                       // p_lds chunk swizzle key

  floatx4 zc;
  zc[0] = zc[1] = zc[2] = zc[3] = 0.f;

  // ---- phase 0: x gather (roll -4 + window) + fp32->bf16 into xo_lds ----
#pragma unroll 1
  for (int i = tid; i < 49 * 48; i += 768) {
    int row = i / 48, c8 = (i - row * 48) * 8;
    int so = src_off(win * 49 + row) + c8;
    floatx4 a = *(const floatx4*)(x + so);
    floatx4 b = *(const floatx4*)(x + so + 4);
    union { __hip_bfloat16 h[8]; short8 s; } u;
#pragma unroll
    for (int e = 0; e < 4; ++e) {
      u.h[e]     = __float2bfloat16(a[e]);
      u.h[4 + e] = __float2bfloat16(b[e]);
    }
    *(short8*)&xo_lds[row][c8] = u.s;
  }
  __syncthreads();

  // ---- phase 1: per-window QKV GEMM. wave w -> cols [w*96, w*96+96).
  // waves 0-3: q (scaled) -> q_lds; 4-7: k -> k_lds; 8-11: v (C^T) -> vt.
  {
    const bool isv = (wv >= 8);
    const bool isq = (wv < 4);
    __hip_bfloat16* dst = isq ? &q_lds[0][0] : &k_lds[0][0];
#pragma unroll 1
    for (int pass = 0; pass < 2; ++pass) {
      int n0 = wv * 96 + pass * 48;
      floatx4 acc[12];
#pragma unroll
      for (int i = 0; i < 12; ++i) acc[i] = zc;

      // manual prefetch: W B-frags for ks+1 loaded inside rolled loop
      bf16x8 bf[3];
#pragma unroll
      for (int ni = 0; ni < 3; ++ni)
        bf[ni] = *(const bf16x8*)(wq + (size_t)(n0 + ni * 16 + q16) * 384 + g * 8);
#pragma unroll 1
      for (int ks = 0; ks < 12; ++ks) {
        int k0 = ks * 32;
        int k0n = (ks < 11 ? ks + 1 : 11) * 32;   // clamped prefetch
        bf16x8 bfn[3];
#pragma unroll
        for (int ni = 0; ni < 3; ++ni)
          bfn[ni] = *(const bf16x8*)(wq + (size_t)(n0 + ni * 16 + q16) * 384 + k0n + g * 8);
        bf16x8 af[4];
#pragma unroll
        for (int mi = 0; mi < 4; ++mi) {
          int row = mi * 16 + q16;
          row = row < 49 ? row : 48;              // pad rows -> dup (discarded)
          af[mi] = *(const bf16x8*)&xo_lds[row][k0 + g * 8];
        }
        __builtin_amdgcn_s_setprio(1);
        if (!isv) {
#pragma unroll
          for (int mi = 0; mi < 4; ++mi)
#pragma unroll
            for (int ni = 0; ni < 3; ++ni)
              acc[mi * 3 + ni] = MFMA16(af[mi], bf[ni], acc[mi * 3 + ni]);
        } else {
          // swapped: C^T[d][t]; A = W rows (d), B = x rows (t)
#pragma unroll
          for (int ai = 0; ai < 3; ++ai)
#pragma unroll
            for (int bj = 0; bj < 4; ++bj)
              acc[ai * 4 + bj] = MFMA16(bf[ai], af[bj], acc[ai * 4 + bj]);
        }
        __builtin_amdgcn_s_setprio(0);
#pragma unroll
        for (int ni = 0; ni < 3; ++ni) bf[ni] = bfn[ni];
      }

      if (!isv) {
        // q/k: C[m][n], lanes q16 -> consecutive n. Guard m<49 (LDS bounds).
#pragma unroll 1
        for (int ni = 0; ni < 3; ++ni) {
          int n = n0 + ni * 16 + q16;
          float bn = bqkv[n];
          int nn = isq ? n : (n - 384);
#pragma unroll
          for (int mi = 0; mi < 4; ++mi) {
#pragma unroll
            for (int r = 0; r < 4; ++r) {
              int m = mi * 16 + g * 4 + r;
              if (m < 49) {
                float v = acc[mi * 3 + ni][r] + bn;
                if (isq) v *= 0.17677669529663687f;   // 1/sqrt(32)
                dst[m * 392 + nn] = __float2bfloat16(v);
              }
            }
          }
        }
      } else {
        // v: C^T[d][t], lanes q16 -> consecutive t (32B runs into vt rows);
        // pad cols t=49..63 get finite garbage, multiplied by P == 0 later.
#pragma unroll 1
        for (int ai = 0; ai < 3; ++ai) {
#pragma unroll
          for (int r = 0; r < 4; ++r) {
            int n = n0 + ai * 16 + g * 4 + r;     // 768..1151
            float bn = bqkv[n];
            int d = n - 768;
#pragma unroll
            for (int bj = 0; bj < 4; ++bj) {
              int t = bj * 16 + q16;
              vt[((size_t)win * 384 + d) * 64 + t] =
                  __float2bfloat16(acc[ai * 4 + bj][r] + bn);
            }
          }
        }
      }
    }
  }
  __syncthreads();   // drains vmcnt(0): vt writes visible (same XCD L2)

  // ---- phase 2: attention, one head per wave (swapped QK^T), PER-MI ----
  {
    const int head = wv;
    int wr = win & 63;
    const bool lastrow = ((wr >> 3) == 7);
    const bool lastcol = ((wr & 7) == 7);

    // shift-mask badbits only for boundary windows (uniform branch);
    // pad mask is pre-baked into bias2 = -1e30.
    unsigned long long badbits = 0ull;
    if (lastrow || lastcol) {
#pragma unroll 1
      for (int mi = 0; mi < 4; ++mi) {
        int m = mi * 16 + q16;
        int m7 = m % 7;
        bool m28 = (m >= 28), m74 = (m7 >= 4);
#pragma unroll
        for (int ni = 0; ni < 4; ++ni) {
#pragma unroll
          for (int r = 0; r < 4; ++r) {
            int n = ni * 16 + g * 4 + r;
            bool bad = (lastrow && (m28 != (n >= 28))) ||
                       (lastcol && (m74 != ((n % 7) >= 4)));
            if (bad) badbits |= (1ull << (mi * 16 + ni * 4 + r));
          }
        }
      }
    }

    // K fragments (resident across the mi loop)
    bf16x8 bk[4];
#pragma unroll
    for (int ni = 0; ni < 4; ++ni) {
      int row = ni * 16 + q16;
      row = row < 49 ? row : 48;                // pad rows masked via bias
      bk[ni] = *(const bf16x8*)&k_lds[row][head * 32 + g * 8];
    }

    // V B-frags (written by this block in phase 1; L2-resident)
    const __hip_bfloat16* vp = vt + ((size_t)win * 384 + head * 32) * 64;
    bf16x8 bv[2][2];
#pragma unroll
    for (int ks = 0; ks < 2; ++ks)
#pragma unroll
      for (int n2 = 0; n2 < 2; ++n2)
        bv[ks][n2] = *(const bf16x8*)(vp + (n2 * 16 + q16) * 64 + ks * 32 + g * 8);

    const __hip_bfloat16* b2 = bias2 + (size_t)head * 4096;
    __hip_bfloat16* pw = &p_lds[wv][0][0];

#pragma unroll 1
    for (int mi = 0; mi < 4; ++mi) {
      // A fragment for this mi (q rows)
      int arow = mi * 16 + q16;
      arow = arow < 49 ? arow : 48;
      bf16x8 aqm = *(const bf16x8*)&q_lds[arow][head * 32 + g * 8];

      // S^T for this mi: 4 MFMA (live regs: 16 instead of 64)
      floatx4 stm[4];
      __builtin_amdgcn_s_setprio(1);
#pragma unroll
      for (int ni = 0; ni < 4; ++ni)
        stm[ni] = MFMA16(bk[ni], aqm, zc);
      __builtin_amdgcn_s_setprio(0);

      uint2 braw[4];
#pragma unroll
      for (int ni = 0; ni < 4; ++ni)
        braw[ni] = *(const uint2*)(b2 + (((size_t)mi * 4 + ni) * 64 + l) * 4);

      float vals[4][4];
      float mx = -1e30f;
#pragma unroll
      for (int ni = 0; ni < 4; ++ni) {
#pragma unroll
        for (int r = 0; r < 4; ++r) {
          float bb = (r == 0) ? bf_lo(braw[ni].x) : (r == 1) ? bf_hi(braw[ni].x)
                     : (r == 2) ? bf_lo(braw[ni].y) : bf_hi(braw[ni].y);
          float v = stm[ni][r] + bb;            // pad entries: bb = -1e30
          if ((badbits >> (mi * 16 + ni * 4 + r)) & 1) v = -1e30f;
          vals[ni][r] = v;
          mx = fmaxf(mx, v);
        }
      }
      mx = fmaxf(mx, __shfl_xor(mx, 16));
      mx = fmaxf(mx, __shfl_xor(mx, 32));
      float sum = 0.f;
#pragma unroll
      for (int ni = 0; ni < 4; ++ni) {
#pragma unroll
        for (int r = 0; r < 4; ++r) {
          float p = __expf(vals[ni][r] - mx);   // masked -> exact 0
          vals[ni][r] = p;
          sum += p;
        }
      }
      sum += __shfl_xor(sum, 16);
      sum += __shfl_xor(sum, 32);
      float inv = 1.0f / sum;

      // normalized P -> swizzled 8B writes (R12 layout)
#pragma unroll
      for (int ni = 0; ni < 4; ++ni) {
        union { __hip_bfloat16 h[4]; unsigned long long u; } pk;
#pragma unroll
        for (int r = 0; r < 4; ++r) pk.h[r] = __float2bfloat16(vals[ni][r] * inv);
        int pc = (2 * ni + (g >> 1)) ^ sw;
        *(unsigned long long*)(pw + q16 * 64 + pc * 8 + (g & 1) * 4) = pk.u;
      }

      // PV for this mi-tile (same-wave LDS RAW/WAR: compiler inserts waits).
      bf16x8 av0 = *(const bf16x8*)(pw + q16 * 64 + (g ^ sw) * 8);
      bf16x8 av1 = *(const bf16x8*)(pw + q16 * 64 + ((4 + g) ^ sw) * 8);
      floatx4 o2[2];
      o2[0] = o2[1] = zc;
#pragma unroll
      for (int n2 = 0; n2 < 2; ++n2) {
        o2[n2] = MFMA16(av0, bv[0][n2], o2[n2]);
        o2[n2] = MFMA16(av1, bv[1][n2], o2[n2]);
      }
#pragma unroll
      for (int r = 0; r < 4; ++r) {
        int m = mi * 16 + g * 4 + r;
        if (m < 49) {
#pragma unroll
          for (int n2 = 0; n2 < 2; ++n2)
            xo_lds[m][head * 32 + n2 * 16 + q16] = __float2bfloat16(o2[n2][r]);
        }
      }
    }
  }
  __syncthreads();                              // all heads' O in xo_lds

  // ---- phase 3: proj. wave wv -> output cols [wv*32, wv*32+32), rolled ----
  {
    floatx4 pacc[4][2];
#pragma unroll
    for (int i = 0; i < 4; ++i)
#pragma unroll
      for (int j = 0; j < 2; ++j) pacc[i][j] = zc;

    const __hip_bfloat16* wpb = wp + (size_t)(wv * 32 + q16) * 384 + g * 8;
    bf16x8 bfr[2];
#pragma unroll
    for (int ni = 0; ni < 2; ++ni)
      bfr[ni] = *(const bf16x8*)(wpb + ni * 16 * 384);

#pragma unroll 1
    for (int kk = 0; kk < 12; ++kk) {
      int k0 = kk * 32;
      int k0n = (kk < 11 ? kk + 1 : 11) * 32;   // clamped prefetch
      bf16x8 bfn[2];
#pragma unroll
      for (int ni = 0; ni < 2; ++ni)
        bfn[ni] = *(const bf16x8*)(wpb + ni * 16 * 384 + k0n);
      bf16x8 af[4];
#pragma unroll
      for (int mi = 0; mi < 4; ++mi) {
        int row = mi * 16 + q16;
        row = row < 49 ? row : 48;
        af[mi] = *(const bf16x8*)&xo_lds[row][k0 + g * 8];
      }
      __builtin_amdgcn_s_setprio(1);
#pragma unroll
      for (int mi = 0; mi < 4; ++mi)
#pragma unroll
        for (int ni = 0; ni < 2; ++ni)
          pacc[mi][ni] = MFMA16(af[mi], bfr[ni], pacc[mi][ni]);
      __builtin_amdgcn_s_setprio(0);
#pragma unroll
      for (int ni = 0; ni < 2; ++ni) bfr[ni] = bfn[ni];
    }

#pragma unroll 1
    for (int mi = 0; mi < 4; ++mi) {
#pragma unroll
      for (int r = 0; r < 4; ++r) {
        int m = mi * 16 + g * 4 + r;
        if (m < 49) {
          int off = dst_off(win * 49 + m);
#pragma unroll
          for (int ni = 0; ni < 2; ++ni) {
            int n = wv * 32 + ni * 16 + q16;
            out[off + n] = pacc[mi][ni][r] + bproj[n];
          }
        }
      }
    }
  }
}

// ---------------------------------------------------------------------------
extern "C" void kernel_launch(void* const* d_in, const int* in_sizes, int n_in,
                              void* d_out, int out_size, void* d_ws, size_t ws_size,
                              hipStream_t stream) {
  const float* x         = (const float*)d_in[0];
  const float* w_qkv     = (const float*)d_in[1];
  const float* b_qkv     = (const float*)d_in[2];
  const float* w_proj    = (const float*)d_in[3];
  const float* b_proj    = (const float*)d_in[4];
  const float* rel_table = (const float*)d_in[5];
  float* out = (float*)d_out;

  char* ws = (char*)d_ws;
  // Workspace layout (total 102,236,160 B):
  const size_t OFF_WQKV  = 0;                        //   884,736
  const size_t OFF_WPROJ = 884736;                   //   294,912
  const size_t OFF_BIAS2 = 1179648;                  //   393,216
  const size_t OFF_VT    = 1572864;                  // 100,663,296 (v^T, 64-pad)

  __hip_bfloat16* wqkv_bf  = (__hip_bfloat16*)(ws + OFF_WQKV);
  __hip_bfloat16* wproj_bf = (__hip_bfloat16*)(ws + OFF_WPROJ);
  __hip_bfloat16* bias2    = (__hip_bfloat16*)(ws + OFF_BIAS2);
  __hip_bfloat16* vt       = (__hip_bfloat16*)(ws + OFF_VT);

  // vt is fully rewritten each call in phase 1 before any read; its pad cols
  // only ever multiply exactly-zero P entries.

  prep_kernel<<<3072, 256, 0, stream>>>(w_qkv, w_proj, rel_table, wqkv_bf, wproj_bf, bias2);
  mega_kernel<<<2048, 768, 0, stream>>>(x, wqkv_bf, b_qkv, bias2, wproj_bf, b_proj, vt, out);
}

// Round 16
// 399.923 us; speedup vs baseline: 5.5717x; 1.5453x over previous
//
#include <hip/hip_runtime.h>
#include <hip/hip_bf16.h>

// ---------------------------------------------------------------------------
// Swin window attention, MI355X gfx950 — MEGA-FUSED v4 (= R13 + pass ILP).
// prep (bf16 weights + pad-premasked frag bias) ->
// mega (per-window: x gather -> LDS; QKV GEMM with W from L2, q/k -> LDS,
//       v^T -> global vt; attention (swapped QK^T, lane-local softmax);
//       proj from LDS -> rolled fp32 scatter to out).
// v4: phase-1's two independent 48-col passes are UNROLLED TOGETHER (was
// serial) -> 2x independent MFMA/load chains in the stalliest phase.
// R15's rolled-loop experiment (I-cache hypothesis) regressed 440->670 and
// is reverted: full unroll + compiler scheduling wins for this family.
// Workspace: 102.2 MB. LDS: 139.8 KB -> 1 block (12 waves)/CU.
// ---------------------------------------------------------------------------

typedef __bf16 bf16x8 __attribute__((ext_vector_type(8)));
typedef float  floatx4 __attribute__((ext_vector_type(4)));
typedef short  short8  __attribute__((ext_vector_type(8)));

#define MFMA16(a, b, c) __builtin_amdgcn_mfma_f32_16x16x32_bf16((a), (b), (c), 0, 0, 0)

static __device__ __forceinline__ int src_off(int gm) {
  int win = gm / 49, t = gm - win * 49;
  int b = win >> 6, rr = win & 63;
  int wi = rr >> 3, wj = rr & 7;
  int ty = t / 7, tx = t - ty * 7;
  int y = wi * 7 + ty + 4; if (y >= 56) y -= 56;
  int x = wj * 7 + tx + 4; if (x >= 56) x -= 56;
  return ((b * 56 + y) * 56 + x) * 384;
}

static __device__ __forceinline__ int dst_off(int gm) {
  int win = gm / 49, t = gm - win * 49;
  int b = win >> 6, rr = win & 63;
  int wi = rr >> 3, wj = rr & 7;
  int ty = t / 7, tx = t - ty * 7;
  int y = wi * 7 + ty + 3; if (y >= 56) y -= 56;
  int x = wj * 7 + tx + 3; if (x >= 56) x -= 56;
  return ((b * 56 + y) * 56 + x) * 384;
}

static __device__ __forceinline__ float bf_lo(unsigned u) {
  union { unsigned v; float f; } c; c.v = u << 16; return c.f;
}
static __device__ __forceinline__ float bf_hi(unsigned u) {
  union { unsigned v; float f; } c; c.v = u & 0xFFFF0000u; return c.f;
}

// ---------------------------------------------------------------------------
// prep: bf16 weight copies + bias2 in the TRANSPOSED (S^T) fragment layout,
// PRE-MASKED with the pad mask (m>=49 || n>=49 -> -1e30).
// bias2[head][mi][ni][lane(64)][r(4)], m = mi*16+(lane&15),
// n = ni*16+(lane>>4)*4+r.
__global__ __launch_bounds__(256) void prep_kernel(
    const float* __restrict__ w_qkv, const float* __restrict__ w_proj,
    const float* __restrict__ rel_table,
    __hip_bfloat16* __restrict__ wqkv_bf, __hip_bfloat16* __restrict__ wproj_bf,
    __hip_bfloat16* __restrict__ bias2) {
  const int N1 = 3 * 384 * 384;   // 442368
  const int N2 = 384 * 384;       // 147456
  const int N3 = 12 * 4 * 4 * 64 * 4;  // 196608
  int i = blockIdx.x * 256 + threadIdx.x;  // grid 3072*256 = N1+N2+N3
  if (i < N1) wqkv_bf[i] = __float2bfloat16(w_qkv[i]);
  int j = i - N1;
  if (j >= 0 && j < N2) wproj_bf[j] = __float2bfloat16(w_proj[j]);
  int k = i - N1 - N2;
  if (k >= 0 && k < N3) {
    int r = k & 3;
    int lp = (k >> 2) & 63;
    int ni = (k >> 8) & 3;
    int mi = (k >> 10) & 3;
    int head = k >> 12;
    int m = mi * 16 + (lp & 15);
    int n = ni * 16 + (lp >> 4) * 4 + r;
    float val = -1e30f;
    if (m < 49 && n < 49) {
      int dy = m / 7 - n / 7 + 6;
      int dx = m % 7 - n % 7 + 6;
      val = rel_table[(dy * 13 + dx) * 12 + head];
    }
    bias2[k] = __float2bfloat16(val);
  }
}

// ---------------------------------------------------------------------------
// Mega kernel v4: 1 block = 1 window, 768 threads = 12 waves.
// LDS: xo(49x392, x then O) + q(49x392) + k(49x392) + p(12x16x64 swizzled)
//    = 139,824 B -> 1 block/CU, 3 waves/SIMD.
__global__ __launch_bounds__(768, 3) void mega_kernel(
    const float* __restrict__ x, const __hip_bfloat16* __restrict__ wq,
    const float* __restrict__ bqkv, const __hip_bfloat16* __restrict__ bias2,
    const __hip_bfloat16* __restrict__ wp, const float* __restrict__ bproj,
    __hip_bfloat16* __restrict__ vt, float* __restrict__ out) {
  __shared__ __hip_bfloat16 xo_lds[49][392];    // 38,416 B (x, later O)
  __shared__ __hip_bfloat16 q_lds[49][392];     // 38,416 B (q, pre-scaled)
  __shared__ __hip_bfloat16 k_lds[49][392];     // 38,416 B
  __shared__ __hip_bfloat16 p_lds[12][16][64];  // 24,576 B (chunk-swizzled)

  int blk = blockIdx.x;                         // 2048 = 8 * 256
  int win = (blk & 7) * 256 + (blk >> 3);       // XCD-chunked swizzle
  int tid = threadIdx.x;
  int wv = tid >> 6, l = tid & 63;              // wave 0..11
  int g = l >> 4, q16 = l & 15;
  const int sw = q16 & 7;                       // p_lds chunk swizzle key

  floatx4 zc;
  zc[0] = zc[1] = zc[2] = zc[3] = 0.f;

  // ---- phase 0: x gather (roll -4 + window) + fp32->bf16 into xo_lds ----
  for (int i = tid; i < 49 * 48; i += 768) {
    int row = i / 48, c8 = (i - row * 48) * 8;
    int so = src_off(win * 49 + row) + c8;
    floatx4 a = *(const floatx4*)(x + so);
    floatx4 b = *(const floatx4*)(x + so + 4);
    union { __hip_bfloat16 h[8]; short8 s; } u;
#pragma unroll
    for (int e = 0; e < 4; ++e) {
      u.h[e]     = __float2bfloat16(a[e]);
      u.h[4 + e] = __float2bfloat16(b[e]);
    }
    *(short8*)&xo_lds[row][c8] = u.s;
  }
  __syncthreads();

  // ---- phase 1: per-window QKV GEMM. wave w -> output cols [w*96,w*96+96).
  // waves 0-3: q (scaled, ->q_lds), 4-7: k (->k_lds), 8-11: v (C^T -> vt).
  // v4: BOTH 48-col passes unrolled together -> 2x independent chains.
  {
    const bool isv = (wv >= 8);
    const bool isq = (wv < 4);
    __hip_bfloat16* dst = isq ? &q_lds[0][0] : &k_lds[0][0];
#pragma unroll 2
    for (int pass = 0; pass < 2; ++pass) {
      int n0 = wv * 96 + pass * 48;
      floatx4 acc[12];
#pragma unroll
      for (int i = 0; i < 12; ++i) acc[i] = zc;

#pragma unroll
      for (int ks = 0; ks < 12; ++ks) {
        int k0 = ks * 32;
        bf16x8 af[4], bf[3];
#pragma unroll
        for (int mi = 0; mi < 4; ++mi) {
          int row = mi * 16 + q16;
          row = row < 49 ? row : 48;            // pad rows -> dup (discarded)
          af[mi] = *(const bf16x8*)&xo_lds[row][k0 + g * 8];
        }
#pragma unroll
        for (int ni = 0; ni < 3; ++ni)
          bf[ni] = *(const bf16x8*)(wq + (size_t)(n0 + ni * 16 + q16) * 384 + k0 + g * 8);
        __builtin_amdgcn_s_setprio(1);
        if (!isv) {
#pragma unroll
          for (int mi = 0; mi < 4; ++mi)
#pragma unroll
            for (int ni = 0; ni < 3; ++ni)
              acc[mi * 3 + ni] = MFMA16(af[mi], bf[ni], acc[mi * 3 + ni]);
        } else {
          // swapped: C^T[d][t]; A = W rows (d), B = x rows (t)
#pragma unroll
          for (int ai = 0; ai < 3; ++ai)
#pragma unroll
            for (int bj = 0; bj < 4; ++bj)
              acc[ai * 4 + bj] = MFMA16(bf[ai], af[bj], acc[ai * 4 + bj]);
        }
        __builtin_amdgcn_s_setprio(0);
      }

      if (!isv) {
        // q/k: C[m][n], lanes q16 -> consecutive n. Guard m<49 (LDS bounds!).
#pragma unroll
        for (int ni = 0; ni < 3; ++ni) {
          int n = n0 + ni * 16 + q16;
          float bn = bqkv[n];
          int nn = isq ? n : (n - 384);
#pragma unroll
          for (int mi = 0; mi < 4; ++mi) {
#pragma unroll
            for (int r = 0; r < 4; ++r) {
              int m = mi * 16 + g * 4 + r;
              if (m < 49) {
                float v = acc[mi * 3 + ni][r] + bn;
                if (isq) v *= 0.17677669529663687f;   // 1/sqrt(32)
                dst[m * 392 + nn] = __float2bfloat16(v);
              }
            }
          }
        }
      } else {
        // v: C^T[d][t], lanes q16 -> consecutive t; write all t (pad cols
        // carry garbage-but-finite values, later multiplied by P == 0).
#pragma unroll
        for (int ai = 0; ai < 3; ++ai) {
#pragma unroll
          for (int r = 0; r < 4; ++r) {
            int n = n0 + ai * 16 + g * 4 + r;     // 768..1151
            float bn = bqkv[n];
            int d = n - 768;
#pragma unroll
            for (int bj = 0; bj < 4; ++bj) {
              int t = bj * 16 + q16;
              vt[((size_t)win * 384 + d) * 64 + t] =
                  __float2bfloat16(acc[ai * 4 + bj][r] + bn);
            }
          }
        }
      }
    }
  }
  __syncthreads();   // drains vmcnt(0): vt writes visible (same XCD L2)

  // ---- phase 2: attention, one head per wave (swapped QK^T) ----
  {
    const int head = wv;
    int wr = win & 63;
    const bool lastrow = ((wr >> 3) == 7);
    const bool lastcol = ((wr & 7) == 7);

    // shift-mask badbits only for the boundary windows (uniform branch);
    // pad mask (m>=49 || n>=49) is pre-baked into bias2 = -1e30.
    unsigned long long badbits = 0ull;
    if (lastrow || lastcol) {
#pragma unroll
      for (int mi = 0; mi < 4; ++mi) {
        int m = mi * 16 + q16;
        int m7 = m % 7;
        bool m28 = (m >= 28), m74 = (m7 >= 4);
#pragma unroll
        for (int ni = 0; ni < 4; ++ni) {
#pragma unroll
          for (int r = 0; r < 4; ++r) {
            int n = ni * 16 + g * 4 + r;
            bool bad = (lastrow && (m28 != (n >= 28))) ||
                       (lastcol && (m74 != ((n % 7) >= 4)));
            if (bad) badbits |= (1ull << (mi * 16 + ni * 4 + r));
          }
        }
      }
    }

    bf16x8 aq[4], bk[4];
#pragma unroll
    for (int mi = 0; mi < 4; ++mi) {
      int row = mi * 16 + q16;
      row = row < 49 ? row : 48;                // pad rows masked via bias
      aq[mi] = *(const bf16x8*)&q_lds[row][head * 32 + g * 8];
      bk[mi] = *(const bf16x8*)&k_lds[row][head * 32 + g * 8];
    }

    floatx4 st[4][4];                           // [ni][mi] = S^T
    __builtin_amdgcn_s_setprio(1);
#pragma unroll
    for (int ni = 0; ni < 4; ++ni)
#pragma unroll
      for (int mi = 0; mi < 4; ++mi)
        st[ni][mi] = MFMA16(bk[ni], aq[mi], zc);
    __builtin_amdgcn_s_setprio(0);

    // V B-frags (vt written by this block in phase 1; L2-resident)
    const __hip_bfloat16* vp = vt + ((size_t)win * 384 + head * 32) * 64;
    bf16x8 bv[2][2];
#pragma unroll
    for (int ks = 0; ks < 2; ++ks)
#pragma unroll
      for (int n2 = 0; n2 < 2; ++n2)
        bv[ks][n2] = *(const bf16x8*)(vp + (n2 * 16 + q16) * 64 + ks * 32 + g * 8);

    const __hip_bfloat16* b2 = bias2 + (size_t)head * 4096;
    __hip_bfloat16* pw = &p_lds[wv][0][0];

#pragma unroll
    for (int mi = 0; mi < 4; ++mi) {
      uint2 braw[4];
#pragma unroll
      for (int ni = 0; ni < 4; ++ni)
        braw[ni] = *(const uint2*)(b2 + ((mi * 4 + ni) * 64 + l) * 4);

      float vals[4][4];
      float mx = -1e30f;
#pragma unroll
      for (int ni = 0; ni < 4; ++ni) {
#pragma unroll
        for (int r = 0; r < 4; ++r) {
          float bb = (r == 0) ? bf_lo(braw[ni].x) : (r == 1) ? bf_hi(braw[ni].x)
                     : (r == 2) ? bf_lo(braw[ni].y) : bf_hi(braw[ni].y);
          float v = st[ni][mi][r] + bb;         // pad entries: bb = -1e30
          if ((badbits >> (mi * 16 + ni * 4 + r)) & 1) v = -1e30f;
          vals[ni][r] = v;
          mx = fmaxf(mx, v);
        }
      }
      mx = fmaxf(mx, __shfl_xor(mx, 16));
      mx = fmaxf(mx, __shfl_xor(mx, 32));
      float sum = 0.f;
#pragma unroll
      for (int ni = 0; ni < 4; ++ni) {
#pragma unroll
        for (int r = 0; r < 4; ++r) {
          float p = __expf(vals[ni][r] - mx);   // masked -> exact 0
          vals[ni][r] = p;
          sum += p;
        }
      }
      sum += __shfl_xor(sum, 16);
      sum += __shfl_xor(sum, 32);
      float inv = 1.0f / sum;

      // normalized P -> swizzled 8B writes (R12 layout)
#pragma unroll
      for (int ni = 0; ni < 4; ++ni) {
        union { __hip_bfloat16 h[4]; unsigned long long u; } pk;
#pragma unroll
        for (int r = 0; r < 4; ++r) pk.h[r] = __float2bfloat16(vals[ni][r] * inv);
        int pc = (2 * ni + (g >> 1)) ^ sw;
        *(unsigned long long*)(pw + q16 * 64 + pc * 8 + (g & 1) * 4) = pk.u;
      }

      bf16x8 av0 = *(const bf16x8*)(pw + q16 * 64 + (g ^ sw) * 8);
      bf16x8 av1 = *(const bf16x8*)(pw + q16 * 64 + ((4 + g) ^ sw) * 8);
      floatx4 o2[2];
      o2[0] = o2[1] = zc;
#pragma unroll
      for (int n2 = 0; n2 < 2; ++n2) {
        o2[n2] = MFMA16(av0, bv[0][n2], o2[n2]);
        o2[n2] = MFMA16(av1, bv[1][n2], o2[n2]);
      }
#pragma unroll
      for (int r = 0; r < 4; ++r) {
        int m = mi * 16 + g * 4 + r;
        if (m < 49) {
#pragma unroll
          for (int n2 = 0; n2 < 2; ++n2)
            xo_lds[m][head * 32 + n2 * 16 + q16] = __float2bfloat16(o2[n2][r]);
        }
      }
    }
  }
  __syncthreads();                              // all heads' O in xo_lds

  // ---- phase 3: proj. wave wv -> output cols [wv*32, wv*32+32) ----
  {
    floatx4 pacc[4][2];
#pragma unroll
    for (int i = 0; i < 4; ++i)
#pragma unroll
      for (int j = 0; j < 2; ++j) pacc[i][j] = zc;

    for (int k0 = 0; k0 < 384; k0 += 32) {
      bf16x8 af[4], bfr[2];
#pragma unroll
      for (int mi = 0; mi < 4; ++mi) {
        int row = mi * 16 + q16;
        row = row < 49 ? row : 48;
        af[mi] = *(const bf16x8*)&xo_lds[row][k0 + g * 8];
      }
#pragma unroll
      for (int ni = 0; ni < 2; ++ni) {
        int brow = wv * 32 + ni * 16 + q16;
        bfr[ni] = *(const bf16x8*)(wp + (size_t)brow * 384 + k0 + g * 8);
      }
      __builtin_amdgcn_s_setprio(1);
#pragma unroll
      for (int mi = 0; mi < 4; ++mi)
#pragma unroll
        for (int ni = 0; ni < 2; ++ni)
          pacc[mi][ni] = MFMA16(af[mi], bfr[ni], pacc[mi][ni]);
      __builtin_amdgcn_s_setprio(0);
    }

#pragma unroll
    for (int mi = 0; mi < 4; ++mi) {
#pragma unroll
      for (int r = 0; r < 4; ++r) {
        int m = mi * 16 + g * 4 + r;
        if (m < 49) {
          int off = dst_off(win * 49 + m);
#pragma unroll
          for (int ni = 0; ni < 2; ++ni) {
            int n = wv * 32 + ni * 16 + q16;
            out[off + n] = pacc[mi][ni][r] + bproj[n];
          }
        }
      }
    }
  }
}

// ---------------------------------------------------------------------------
extern "C" void kernel_launch(void* const* d_in, const int* in_sizes, int n_in,
                              void* d_out, int out_size, void* d_ws, size_t ws_size,
                              hipStream_t stream) {
  const float* x         = (const float*)d_in[0];
  const float* w_qkv     = (const float*)d_in[1];
  const float* b_qkv     = (const float*)d_in[2];
  const float* w_proj    = (const float*)d_in[3];
  const float* b_proj    = (const float*)d_in[4];
  const float* rel_table = (const float*)d_in[5];
  float* out = (float*)d_out;

  char* ws = (char*)d_ws;
  // Workspace layout (total 102,236,160 B):
  const size_t OFF_WQKV  = 0;                        //   884,736
  const size_t OFF_WPROJ = 884736;                   //   294,912
  const size_t OFF_BIAS2 = 1179648;                  //   393,216
  const size_t OFF_VT    = 1572864;                  // 100,663,296 (v^T, 64-pad)

  __hip_bfloat16* wqkv_bf  = (__hip_bfloat16*)(ws + OFF_WQKV);
  __hip_bfloat16* wproj_bf = (__hip_bfloat16*)(ws + OFF_WPROJ);
  __hip_bfloat16* bias2    = (__hip_bfloat16*)(ws + OFF_BIAS2);
  __hip_bfloat16* vt       = (__hip_bfloat16*)(ws + OFF_VT);

  // vt is fully rewritten each call in phase 1 before any read; its pad cols
  // only ever multiply exactly-zero P entries.

  prep_kernel<<<3072, 256, 0, stream>>>(w_qkv, w_proj, rel_table, wqkv_bf, wproj_bf, bias2);
  mega_kernel<<<2048, 768, 0, stream>>>(x, wqkv_bf, b_qkv, bias2, wproj_bf, b_proj, vt, out);
}